// Round 1
// baseline (968.978 us; speedup 1.0000x reference)
//
#include <hip/hip_runtime.h>
#include <math.h>

// Problem constants
#define L_SEQ   32768
#define H_DIM   256
#define P_DIM   128
#define P2      256      // 2*P interleaved (re,im)
#define T_CHUNK 32
#define G_CHUNKS 1024    // L_SEQ / T_CHUNK

// workspace layout (float offsets)
#define WS_BBART 0                    // [H][P2]   65536
#define WS_WT    65536                // [P2][H]   65536
#define WS_LB    131072               // 2P        256
#define WS_AT    131328               // 2P        256
#define WS_COEF  131584               // 2P        256
#define WS_XEND  131840               // [G][P2]   262144
#define WS_CARRY (131840 + 262144)    // [G][P2]   262144
// total = 656128 floats = ~2.6 MB

// ---------------------------------------------------------------------------
// Setup 1: per-p quantities. 1 block, 128 threads.
__global__ void k_setup_p(const float* __restrict__ lre, const float* __restrict__ lim,
                          const float* __restrict__ lstep, float* __restrict__ ws) {
    int p = threadIdx.x;
    if (p >= P_DIM) return;
    float step = expf(lstep[p]);
    float lr = lre[p], li = lim[p];
    float z = lr * step, y = li * step;
    float er = expf(z);
    float lbr = er * cosf(y);
    float lbi = er * sinf(y);
    ws[WS_LB + 2*p]     = lbr;
    ws[WS_LB + 2*p + 1] = lbi;
    // A^T = Lambda_bar^T, computed in double (large angle => fp32 arg reduction bad)
    double zt = (double)z * (double)T_CHUNK;
    double yt = (double)y * (double)T_CHUNK;
    double ed = exp(zt);
    ws[WS_AT + 2*p]     = (float)(ed * cos(yt));
    ws[WS_AT + 2*p + 1] = (float)(ed * sin(yt));
    // coef = (Lambda_bar - 1) / Lambda
    float a = lbr - 1.0f, b = lbi;
    float den = lr*lr + li*li;
    ws[WS_COEF + 2*p]     = (a*lr + b*li) / den;
    ws[WS_COEF + 2*p + 1] = (b*lr - a*li) / den;
}

// ---------------------------------------------------------------------------
// Setup 2: build B_bar_t [h][2p] and W_t [2p][h]. 64 blocks x 256 threads.
__global__ void k_setup_mats(const float* __restrict__ B, const float* __restrict__ C,
                             const float* __restrict__ coef, float* __restrict__ bbart,
                             float* __restrict__ wt) {
    int t = blockIdx.x * blockDim.x + threadIdx.x;   // 0..16383
    for (int e = t; e < P_DIM * H_DIM; e += 64 * 256) {
        int p = e >> 8;          // 0..127
        int h = e & 255;         // 0..255
        float br = B[(size_t)(p*H_DIM + h)*2 + 0];
        float bi = B[(size_t)(p*H_DIM + h)*2 + 1];
        float cr = coef[2*p], ci = coef[2*p + 1];
        bbart[(size_t)h*P2 + 2*p]     = cr*br - ci*bi;
        bbart[(size_t)h*P2 + 2*p + 1] = cr*bi + ci*br;
        float Cr = C[(size_t)(h*P_DIM + p)*2 + 0];
        float Ci = C[(size_t)(h*P_DIM + p)*2 + 1];
        wt[(size_t)(2*p)*H_DIM + h]     =  2.0f * Cr;
        wt[(size_t)(2*p + 1)*H_DIM + h] = -2.0f * Ci;
    }
}

// ---------------------------------------------------------------------------
// fp32 GEMM: C[l][n] = sum_k A[l][k] * Bm[k][n]  (M=32768, N=256, K=256)
// Block tile 128 x 256 (full N) so each block owns its rows exclusively ->
// safe for in-place C==A (reads via LDS staging complete before epilogue writes).
// 256 threads, 8x16 register tile each.
#define SA 132   // LDS stride for As[k][l]  (pad 4 -> <=2-way conflicts)
#define SB 260   // LDS stride for Bs[k][n]  (multiple of 4 -> aligned b128)

template<bool EPI>
__global__ __launch_bounds__(256, 1) void k_gemm(
        const float* A, const float* __restrict__ Bm, float* Cmat,
        const float* __restrict__ Dv, const float* __restrict__ U) {
    __shared__ float As[16 * SA];
    __shared__ float Bs[16 * SB];
    const int t  = threadIdx.x;
    const int tl = t >> 4;    // 0..15 (row group)
    const int tn = t & 15;    // 0..15 (col group)
    const int l0 = blockIdx.x * 128;

    float4 acc[8][4];
    #pragma unroll
    for (int i = 0; i < 8; i++)
        #pragma unroll
        for (int q = 0; q < 4; q++) acc[i][q] = make_float4(0.f, 0.f, 0.f, 0.f);

    for (int k0 = 0; k0 < 256; k0 += 16) {
        // stage A transposed: As[k_local][l]
        #pragma unroll
        for (int j = 0; j < 2; j++) {
            int idx4 = j * 256 + t;          // 0..511 float4s (128 rows x 4)
            int l  = idx4 >> 2;
            int c4 = idx4 & 3;
            const float4 f = *(const float4*)(A + (size_t)(l0 + l) * 256 + k0 + c4 * 4);
            As[(c4*4 + 0) * SA + l] = f.x;
            As[(c4*4 + 1) * SA + l] = f.y;
            As[(c4*4 + 2) * SA + l] = f.z;
            As[(c4*4 + 3) * SA + l] = f.w;
        }
        // stage B natural: Bs[k_local][n]
        #pragma unroll
        for (int j = 0; j < 4; j++) {
            int idx4 = j * 256 + t;          // 0..1023 float4s (16 rows x 64)
            int kk = idx4 >> 6;
            int n4 = idx4 & 63;
            const float4 f = *(const float4*)(Bm + (size_t)(k0 + kk) * 256 + n4 * 4);
            *(float4*)(Bs + kk * SB + n4 * 4) = f;
        }
        __syncthreads();
        #pragma unroll
        for (int kk = 0; kk < 16; kk++) {
            float a[8];
            const float4 a0 = *(const float4*)(As + kk * SA + 8 * tl);
            const float4 a1 = *(const float4*)(As + kk * SA + 8 * tl + 4);
            a[0]=a0.x; a[1]=a0.y; a[2]=a0.z; a[3]=a0.w;
            a[4]=a1.x; a[5]=a1.y; a[6]=a1.z; a[7]=a1.w;
            float4 b[4];
            #pragma unroll
            for (int q = 0; q < 4; q++)
                b[q] = *(const float4*)(Bs + kk * SB + 4 * tn + 64 * q);
            #pragma unroll
            for (int i = 0; i < 8; i++)
                #pragma unroll
                for (int q = 0; q < 4; q++) {
                    acc[i][q].x += a[i] * b[q].x;
                    acc[i][q].y += a[i] * b[q].y;
                    acc[i][q].z += a[i] * b[q].z;
                    acc[i][q].w += a[i] * b[q].w;
                }
        }
        __syncthreads();
    }
    // epilogue (EPI: + D[n]*U[l][n])
    #pragma unroll
    for (int i = 0; i < 8; i++) {
        size_t row = (size_t)l0 + tl * 8 + i;
        #pragma unroll
        for (int q = 0; q < 4; q++) {
            int col = 4 * tn + 64 * q;
            float4 v = acc[i][q];
            if (EPI) {
                const float4 d4 = *(const float4*)(Dv + col);
                const float4 u4 = *(const float4*)(U + row * 256 + col);
                v.x += d4.x * u4.x; v.y += d4.y * u4.y;
                v.z += d4.z * u4.z; v.w += d4.w * u4.w;
            }
            *(float4*)(Cmat + row * 256 + col) = v;
        }
    }
}

// ---------------------------------------------------------------------------
// Scan pass 1: local (zero-carry) scan in place; store chunk-end state.
// grid 256 x 256 threads; 4 chunks per block; thread = (chunk g, lane q)
// lane q handles complex channels 2q, 2q+1 -> float4 at column 4q.
__global__ void k_scan_local(float* __restrict__ bu, float* __restrict__ ws) {
    const int t = threadIdx.x;
    const int g = blockIdx.x * 4 + (t >> 6);
    const int q = t & 63;
    const float4 A = *(const float4*)(ws + WS_LB + 4 * q);  // (a0r,a0i,a1r,a1i)
    float x0r = 0.f, x0i = 0.f, x1r = 0.f, x1i = 0.f;
    float* base = bu + (size_t)g * T_CHUNK * 256 + 4 * q;
    #pragma unroll 8
    for (int i = 0; i < T_CHUNK; i++) {
        float4 f = *(float4*)(base + (size_t)i * 256);
        float n0r = A.x * x0r - A.y * x0i + f.x;
        float n0i = A.x * x0i + A.y * x0r + f.y;
        float n1r = A.z * x1r - A.w * x1i + f.z;
        float n1i = A.z * x1i + A.w * x1r + f.w;
        x0r = n0r; x0i = n0i; x1r = n1r; x1i = n1i;
        *(float4*)(base + (size_t)i * 256) = make_float4(x0r, x0i, x1r, x1i);
    }
    *(float4*)(ws + WS_XEND + (size_t)g * 256 + 4 * q) = make_float4(x0r, x0i, x1r, x1i);
}

// Scan pass 2: sequential carry across G chunks. 1 block, 64 threads.
__global__ void k_scan_carry(float* __restrict__ ws) {
    const int q = threadIdx.x;   // 0..63
    const float4 A = *(const float4*)(ws + WS_AT + 4 * q);  // Lambda_bar^T
    float c0r = 0.f, c0i = 0.f, c1r = 0.f, c1i = 0.f;
    *(float4*)(ws + WS_CARRY + 4 * q) = make_float4(0.f, 0.f, 0.f, 0.f);
    #pragma unroll 8
    for (int g = 1; g < G_CHUNKS; g++) {
        float4 xe = *(const float4*)(ws + WS_XEND + (size_t)(g - 1) * 256 + 4 * q);
        float n0r = A.x * c0r - A.y * c0i + xe.x;
        float n0i = A.x * c0i + A.y * c0r + xe.y;
        float n1r = A.z * c1r - A.w * c1i + xe.z;
        float n1i = A.z * c1i + A.w * c1r + xe.w;
        c0r = n0r; c0i = n0i; c1r = n1r; c1i = n1i;
        *(float4*)(ws + WS_CARRY + (size_t)g * 256 + 4 * q) = make_float4(c0r, c0i, c1r, c1i);
    }
}

// Scan pass 3: x[g*T+i] += A^{i+1} * carry[g], in place.
__global__ void k_scan_apply(float* __restrict__ xs, const float* __restrict__ ws) {
    const int t = threadIdx.x;
    const int g = blockIdx.x * 4 + (t >> 6);
    const int q = t & 63;
    const float4 A = *(const float4*)(ws + WS_LB + 4 * q);
    const float4 c = *(const float4*)(ws + WS_CARRY + (size_t)g * 256 + 4 * q);
    float y0r = c.x, y0i = c.y, y1r = c.z, y1i = c.w;
    float* base = xs + (size_t)g * T_CHUNK * 256 + 4 * q;
    #pragma unroll 8
    for (int i = 0; i < T_CHUNK; i++) {
        float t0r = A.x * y0r - A.y * y0i;
        float t0i = A.x * y0i + A.y * y0r;
        float t1r = A.z * y1r - A.w * y1i;
        float t1i = A.z * y1i + A.w * y1r;
        y0r = t0r; y0i = t0i; y1r = t1r; y1i = t1i;
        float4 f = *(float4*)(base + (size_t)i * 256);
        f.x += y0r; f.y += y0i; f.z += y1r; f.w += y1i;
        *(float4*)(base + (size_t)i * 256) = f;
    }
}

// ---------------------------------------------------------------------------
extern "C" void kernel_launch(void* const* d_in, const int* in_sizes, int n_in,
                              void* d_out, int out_size, void* d_ws, size_t ws_size,
                              hipStream_t stream) {
    const float* lre   = (const float*)d_in[0];  // Lambda_re (P)
    const float* lim   = (const float*)d_in[1];  // Lambda_im (P)
    const float* B     = (const float*)d_in[2];  // (P,H,2)
    const float* C     = (const float*)d_in[3];  // (H,P,2)
    const float* D     = (const float*)d_in[4];  // (H)
    const float* lstep = (const float*)d_in[5];  // (P)
    const float* u     = (const float*)d_in[6];  // (L,H)
    float* out = (float*)d_out;                  // (L,H) -- also Bu/xs scratch
    float* ws  = (float*)d_ws;

    k_setup_p<<<1, 128, 0, stream>>>(lre, lim, lstep, ws);
    k_setup_mats<<<64, 256, 0, stream>>>(B, C, ws + WS_COEF, ws + WS_BBART, ws + WS_WT);
    // Bu = u @ B_bar_t^T  -> into d_out
    k_gemm<false><<<256, 256, 0, stream>>>(u, ws + WS_BBART, out, nullptr, nullptr);
    // chunked linear scan in place over d_out
    k_scan_local<<<256, 256, 0, stream>>>(out, ws);
    k_scan_carry<<<1, 64, 0, stream>>>(ws);
    k_scan_apply<<<256, 256, 0, stream>>>(out, ws);
    // out = xs @ W_t + D*u  (in place, row-exclusive blocks)
    k_gemm<true><<<256, 256, 0, stream>>>(out, ws + WS_WT, out, D, u);
}

// Round 2
// 255.781 us; speedup vs baseline: 3.7883x; 3.7883x over previous
//
#include <hip/hip_runtime.h>
#include <math.h>

// Problem constants
#define L_SEQ   32768
#define H_DIM   256
#define P_DIM   128
#define P2      256      // 2*P interleaved (re,im)
#define T_CHUNK 32
#define G_CHUNKS 1024    // L_SEQ / T_CHUNK

// workspace layout (float offsets)
#define WS_LB    0                    // 2P        256
#define WS_AT    256                  // 2P        256
#define WS_COEF  512                  // 2P        256
#define WS_XEND  768                  // [G][P2]   262144
#define WS_CARRY (768 + 262144)       // [G][P2]   262144
#define WS_PACKS (768 + 524288)       // ushort packs start here (float offset)
// packs: W1h, W1l, W2h, W2l each [256][256] ushort = 65536 ushorts
// total ws = 525056 + 131072 floats = 656128 floats (~2.6 MB), same as R1

typedef __attribute__((ext_vector_type(8))) short short8;
typedef __attribute__((ext_vector_type(4))) float f32x4;

// ---------------------------------------------------------------------------
__device__ __forceinline__ void split_bf16(float v, ushort& hi, ushort& lo) {
    union { float f; unsigned u; } a; a.f = v;
    unsigned r = a.u + 0x7FFFu + ((a.u >> 16) & 1u);   // RNE to bf16
    hi = (ushort)(r >> 16);
    union { unsigned u; float f; } hf; hf.u = ((unsigned)hi) << 16;
    float rem = v - hf.f;
    union { float f; unsigned u; } b; b.f = rem;
    unsigned r2 = b.u + 0x7FFFu + ((b.u >> 16) & 1u);
    lo = (ushort)(r2 >> 16);
}

// ---------------------------------------------------------------------------
// Setup 1: per-p quantities. 1 block, 128 threads.
__global__ void k_setup_p(const float* __restrict__ lre, const float* __restrict__ lim,
                          const float* __restrict__ lstep, float* __restrict__ ws) {
    int p = threadIdx.x;
    if (p >= P_DIM) return;
    float step = expf(lstep[p]);
    float lr = lre[p], li = lim[p];
    float z = lr * step, y = li * step;
    float er = expf(z);
    float lbr = er * cosf(y);
    float lbi = er * sinf(y);
    ws[WS_LB + 2*p]     = lbr;
    ws[WS_LB + 2*p + 1] = lbi;
    // A^T = Lambda_bar^T, computed in double (large angle => fp32 arg reduction bad)
    double zt = (double)z * (double)T_CHUNK;
    double yt = (double)y * (double)T_CHUNK;
    double ed = exp(zt);
    ws[WS_AT + 2*p]     = (float)(ed * cos(yt));
    ws[WS_AT + 2*p + 1] = (float)(ed * sin(yt));
    // coef = (Lambda_bar - 1) / Lambda
    float a = lbr - 1.0f, b = lbi;
    float den = lr*lr + li*li;
    ws[WS_COEF + 2*p]     = (a*lr + b*li) / den;
    ws[WS_COEF + 2*p + 1] = (b*lr - a*li) / den;
}

// ---------------------------------------------------------------------------
// Setup 2: build split-bf16 packed weights, layout [n][k] (k contiguous).
// W1: n = p2 (0..255), k = h  (GEMM1: Bu = u @ B_bar_t^T)
// W2: n = h (0..255),  k = p2 (GEMM2: out = xs @ W_t)
__global__ void k_setup_mats(const float* __restrict__ B, const float* __restrict__ C,
                             const float* __restrict__ coef,
                             ushort* __restrict__ w1h, ushort* __restrict__ w1l,
                             ushort* __restrict__ w2h, ushort* __restrict__ w2l) {
    int t = blockIdx.x * blockDim.x + threadIdx.x;   // 0..16383
    for (int e = t; e < P_DIM * H_DIM; e += 64 * 256) {
        int p = e >> 8;          // 0..127
        int h = e & 255;         // 0..255
        float br = B[(size_t)(p*H_DIM + h)*2 + 0];
        float bi = B[(size_t)(p*H_DIM + h)*2 + 1];
        float cr = coef[2*p], ci = coef[2*p + 1];
        float v1r = cr*br - ci*bi;
        float v1i = cr*bi + ci*br;
        ushort hi, lo;
        split_bf16(v1r, hi, lo);
        w1h[(size_t)(2*p)*256 + h] = hi;  w1l[(size_t)(2*p)*256 + h] = lo;
        split_bf16(v1i, hi, lo);
        w1h[(size_t)(2*p+1)*256 + h] = hi; w1l[(size_t)(2*p+1)*256 + h] = lo;
        float Cr = C[(size_t)(h*P_DIM + p)*2 + 0];
        float Ci = C[(size_t)(h*P_DIM + p)*2 + 1];
        split_bf16(2.0f*Cr, hi, lo);
        w2h[(size_t)h*256 + 2*p] = hi;    w2l[(size_t)h*256 + 2*p] = lo;
        split_bf16(-2.0f*Ci, hi, lo);
        w2h[(size_t)h*256 + 2*p+1] = hi;  w2l[(size_t)h*256 + 2*p+1] = lo;
    }
}

// ---------------------------------------------------------------------------
// MFMA split-bf16 GEMM: C[l][n] = sum_k A[l][k] * W[k][n]
// M=32768, N=256 (full N per block -> in-place safe), K=256.
// 512 threads = 8 waves; wave grid 4(M:32) x 2(N:128); per wave 2x8 tiles of
// 16x16 via mfma_f32_16x16x32_bf16. Split products: hh + hl + lh.
#define SAK 40   // LDS k-stride (ushorts): 32 + 8 pad, rows 16B aligned
#define SBK 40

template<bool EPI>
__global__ __launch_bounds__(512, 2) void k_gemm_mfma(
        const float* A, const ushort* __restrict__ Wh, const ushort* __restrict__ Wl,
        float* Cmat, const float* __restrict__ Dv, const float* __restrict__ U) {
    __shared__ ushort Ah[128 * SAK];
    __shared__ ushort Al[128 * SAK];
    __shared__ ushort Bh[256 * SBK];
    __shared__ ushort Bl[256 * SBK];
    const int t      = threadIdx.x;
    const int lane   = t & 63;
    const int wave   = t >> 6;        // 0..7
    const int wm     = wave & 3;      // M quarter (32 rows each)
    const int wn     = wave >> 2;     // N half (128 cols each)
    const int lane16 = lane & 15;
    const int quad   = lane >> 4;
    const int l0     = blockIdx.x * 128;

    f32x4 acc[2][8];
    #pragma unroll
    for (int i = 0; i < 2; i++)
        #pragma unroll
        for (int j = 0; j < 8; j++) acc[i][j] = (f32x4){0.f, 0.f, 0.f, 0.f};

    for (int k0 = 0; k0 < 256; k0 += 32) {
        // stage A (fp32 -> split bf16): 128 rows x 32 k = 1024 float4s, 2/thread
        #pragma unroll
        for (int j = 0; j < 2; j++) {
            int idx = j * 512 + t;
            int m  = idx >> 3;
            int c4 = idx & 7;
            const float4 f = *(const float4*)(A + (size_t)(l0 + m) * 256 + k0 + c4 * 4);
            ushort4 h4, l4;
            split_bf16(f.x, h4.x, l4.x);
            split_bf16(f.y, h4.y, l4.y);
            split_bf16(f.z, h4.z, l4.z);
            split_bf16(f.w, h4.w, l4.w);
            *(ushort4*)(Ah + m * SAK + c4 * 4) = h4;
            *(ushort4*)(Al + m * SAK + c4 * 4) = l4;
        }
        // stage B (already split/packed [n][k]): 256 rows x 32 k -> 1024 16B chunks/pack
        #pragma unroll
        for (int j = 0; j < 2; j++) {
            int idx = j * 512 + t;
            int n = idx >> 2;
            int c = idx & 3;
            *(uint4*)(Bh + n * SBK + c * 8) = *(const uint4*)(Wh + (size_t)n * 256 + k0 + c * 8);
            *(uint4*)(Bl + n * SBK + c * 8) = *(const uint4*)(Wl + (size_t)n * 256 + k0 + c * 8);
        }
        __syncthreads();
        // fragments: a[m=lane16][k=quad*8+j], b[n=lane16][k=quad*8+j]
        short8 ah[2], alo[2], bh[8], blo[8];
        #pragma unroll
        for (int mf = 0; mf < 2; mf++) {
            int m = wm * 32 + mf * 16 + lane16;
            ah[mf]  = *(const short8*)(Ah + m * SAK + quad * 8);
            alo[mf] = *(const short8*)(Al + m * SAK + quad * 8);
        }
        #pragma unroll
        for (int nf = 0; nf < 8; nf++) {
            int n = wn * 128 + nf * 16 + lane16;
            bh[nf]  = *(const short8*)(Bh + n * SBK + quad * 8);
            blo[nf] = *(const short8*)(Bl + n * SBK + quad * 8);
        }
        #pragma unroll
        for (int mf = 0; mf < 2; mf++)
            #pragma unroll
            for (int nf = 0; nf < 8; nf++) {
                acc[mf][nf] = __builtin_amdgcn_mfma_f32_16x16x32_bf16(ah[mf],  bh[nf],  acc[mf][nf], 0, 0, 0);
                acc[mf][nf] = __builtin_amdgcn_mfma_f32_16x16x32_bf16(ah[mf],  blo[nf], acc[mf][nf], 0, 0, 0);
                acc[mf][nf] = __builtin_amdgcn_mfma_f32_16x16x32_bf16(alo[mf], bh[nf],  acc[mf][nf], 0, 0, 0);
            }
        __syncthreads();
    }
    // epilogue: C/D layout col=lane&15, row=quad*4+reg
    #pragma unroll
    for (int mf = 0; mf < 2; mf++) {
        #pragma unroll
        for (int nf = 0; nf < 8; nf++) {
            int row0 = l0 + wm * 32 + mf * 16 + quad * 4;
            int col  = wn * 128 + nf * 16 + lane16;
            #pragma unroll
            for (int r = 0; r < 4; r++) {
                float v = acc[mf][nf][r];
                if (EPI) {
                    v += Dv[col] * U[(size_t)(row0 + r) * 256 + col];
                }
                Cmat[(size_t)(row0 + r) * 256 + col] = v;
            }
        }
    }
}

// ---------------------------------------------------------------------------
// Scan pass 1: local (zero-carry) scan in place; store chunk-end state.
__global__ void k_scan_local(float* __restrict__ bu, float* __restrict__ ws) {
    const int t = threadIdx.x;
    const int g = blockIdx.x * 4 + (t >> 6);
    const int q = t & 63;
    const float4 A = *(const float4*)(ws + WS_LB + 4 * q);  // (a0r,a0i,a1r,a1i)
    float x0r = 0.f, x0i = 0.f, x1r = 0.f, x1i = 0.f;
    float* base = bu + (size_t)g * T_CHUNK * 256 + 4 * q;
    #pragma unroll 8
    for (int i = 0; i < T_CHUNK; i++) {
        float4 f = *(float4*)(base + (size_t)i * 256);
        float n0r = A.x * x0r - A.y * x0i + f.x;
        float n0i = A.x * x0i + A.y * x0r + f.y;
        float n1r = A.z * x1r - A.w * x1i + f.z;
        float n1i = A.z * x1i + A.w * x1r + f.w;
        x0r = n0r; x0i = n0i; x1r = n1r; x1i = n1i;
        *(float4*)(base + (size_t)i * 256) = make_float4(x0r, x0i, x1r, x1i);
    }
    *(float4*)(ws + WS_XEND + (size_t)g * 256 + 4 * q) = make_float4(x0r, x0i, x1r, x1i);
}

// Scan pass 2: sequential carry across G chunks. 1 block, 64 threads.
__global__ void k_scan_carry(float* __restrict__ ws) {
    const int q = threadIdx.x;   // 0..63
    const float4 A = *(const float4*)(ws + WS_AT + 4 * q);  // Lambda_bar^T
    float c0r = 0.f, c0i = 0.f, c1r = 0.f, c1i = 0.f;
    *(float4*)(ws + WS_CARRY + 4 * q) = make_float4(0.f, 0.f, 0.f, 0.f);
    #pragma unroll 8
    for (int g = 1; g < G_CHUNKS; g++) {
        float4 xe = *(const float4*)(ws + WS_XEND + (size_t)(g - 1) * 256 + 4 * q);
        float n0r = A.x * c0r - A.y * c0i + xe.x;
        float n0i = A.x * c0i + A.y * c0r + xe.y;
        float n1r = A.z * c1r - A.w * c1i + xe.z;
        float n1i = A.z * c1i + A.w * c1r + xe.w;
        c0r = n0r; c0i = n0i; c1r = n1r; c1i = n1i;
        *(float4*)(ws + WS_CARRY + (size_t)g * 256 + 4 * q) = make_float4(c0r, c0i, c1r, c1i);
    }
}

// Scan pass 3: x[g*T+i] += A^{i+1} * carry[g], in place.
__global__ void k_scan_apply(float* __restrict__ xs, const float* __restrict__ ws) {
    const int t = threadIdx.x;
    const int g = blockIdx.x * 4 + (t >> 6);
    const int q = t & 63;
    const float4 A = *(const float4*)(ws + WS_LB + 4 * q);
    const float4 c = *(const float4*)(ws + WS_CARRY + (size_t)g * 256 + 4 * q);
    float y0r = c.x, y0i = c.y, y1r = c.z, y1i = c.w;
    float* base = xs + (size_t)g * T_CHUNK * 256 + 4 * q;
    #pragma unroll 8
    for (int i = 0; i < T_CHUNK; i++) {
        float t0r = A.x * y0r - A.y * y0i;
        float t0i = A.x * y0i + A.y * y0r;
        float t1r = A.z * y1r - A.w * y1i;
        float t1i = A.z * y1i + A.w * y1r;
        y0r = t0r; y0i = t0i; y1r = t1r; y1i = t1i;
        float4 f = *(float4*)(base + (size_t)i * 256);
        f.x += y0r; f.y += y0i; f.z += y1r; f.w += y1i;
        *(float4*)(base + (size_t)i * 256) = f;
    }
}

// ---------------------------------------------------------------------------
extern "C" void kernel_launch(void* const* d_in, const int* in_sizes, int n_in,
                              void* d_out, int out_size, void* d_ws, size_t ws_size,
                              hipStream_t stream) {
    const float* lre   = (const float*)d_in[0];  // Lambda_re (P)
    const float* lim   = (const float*)d_in[1];  // Lambda_im (P)
    const float* B     = (const float*)d_in[2];  // (P,H,2)
    const float* C     = (const float*)d_in[3];  // (H,P,2)
    const float* D     = (const float*)d_in[4];  // (H)
    const float* lstep = (const float*)d_in[5];  // (P)
    const float* u     = (const float*)d_in[6];  // (L,H)
    float* out = (float*)d_out;                  // (L,H) -- also Bu/xs scratch
    float* ws  = (float*)d_ws;
    ushort* wpk = (ushort*)(ws + WS_PACKS);
    ushort* w1h = wpk;
    ushort* w1l = wpk + 65536;
    ushort* w2h = wpk + 131072;
    ushort* w2l = wpk + 196608;

    k_setup_p<<<1, 128, 0, stream>>>(lre, lim, lstep, ws);
    k_setup_mats<<<64, 256, 0, stream>>>(B, C, ws + WS_COEF, w1h, w1l, w2h, w2l);
    // Bu = u @ W1  -> into d_out
    k_gemm_mfma<false><<<256, 512, 0, stream>>>(u, w1h, w1l, out, nullptr, nullptr);
    // chunked linear scan in place over d_out
    k_scan_local<<<256, 256, 0, stream>>>(out, ws);
    k_scan_carry<<<1, 64, 0, stream>>>(ws);
    k_scan_apply<<<256, 256, 0, stream>>>(out, ws);
    // out = xs @ W2 + D*u  (in place, row-exclusive full-N blocks)
    k_gemm_mfma<true><<<256, 512, 0, stream>>>(out, w2h, w2l, out, D, u);
}

// Round 3
// 209.732 us; speedup vs baseline: 4.6201x; 1.2196x over previous
//
#include <hip/hip_runtime.h>
#include <math.h>

// Problem constants
#define L_SEQ   32768
#define H_DIM   256
#define P_DIM   128
#define P2      256      // 2*P interleaved (re,im)
#define T_CHUNK 32
#define G_CHUNKS 1024    // L_SEQ / T_CHUNK

// workspace layout (float offsets)
#define WS_LB    0                      // Lambda_bar          256
#define WS_AT    256                    // Lambda_bar^32       256
#define WS_A64   512                    // Lambda_bar^2048     256
#define WS_COEF  768                    // (Lb-1)/Lambda       256
#define WS_APOW  1024                   // [32][P2] Lb^{i+1}   8192
#define WS_XEND  9216                   // [G][P2]             262144
#define WS_CARRY (9216 + 262144)        // [G][P2]             262144
#define WS_PACKS (9216 + 524288)        // ushort packs start (float offset)
// packs: W1h, W1l, W2h, W2l each [256][256] ushort = 65536 ushorts = 131072 floats
// total = 533504 + 131072 = 664576 floats (~2.66 MB)

typedef __attribute__((ext_vector_type(8))) short short8;
typedef __attribute__((ext_vector_type(4))) float f32x4;

// ---------------------------------------------------------------------------
__device__ __forceinline__ void split_bf16(float v, ushort& hi, ushort& lo) {
    union { float f; unsigned u; } a; a.f = v;
    unsigned r = a.u + 0x7FFFu + ((a.u >> 16) & 1u);   // RNE to bf16
    hi = (ushort)(r >> 16);
    union { unsigned u; float f; } hf; hf.u = ((unsigned)hi) << 16;
    float rem = v - hf.f;
    union { float f; unsigned u; } b; b.f = rem;
    unsigned r2 = b.u + 0x7FFFu + ((b.u >> 16) & 1u);
    lo = (ushort)(r2 >> 16);
}

// ---------------------------------------------------------------------------
// Setup 1: per-p quantities. 1 block, 128 threads.
__global__ void k_setup_p(const float* __restrict__ lre, const float* __restrict__ lim,
                          const float* __restrict__ lstep, float* __restrict__ ws) {
    int p = threadIdx.x;
    if (p >= P_DIM) return;
    float step = expf(lstep[p]);
    float lr = lre[p], li = lim[p];
    float z = lr * step, y = li * step;
    float er = expf(z);
    ws[WS_LB + 2*p]     = er * cosf(y);
    ws[WS_LB + 2*p + 1] = er * sinf(y);
    // powers in double (large angle => fp32 arg reduction bad)
    double zd = (double)z, yd = (double)y;
    // A^T = Lb^32 (per-chunk advance)
    {
        double ed = exp(zd * 32.0);
        ws[WS_AT + 2*p]     = (float)(ed * cos(yd * 32.0));
        ws[WS_AT + 2*p + 1] = (float)(ed * sin(yd * 32.0));
    }
    // A64 = Lb^2048 (per-segment advance, 64 chunks)
    {
        double ed = exp(zd * 2048.0);
        ws[WS_A64 + 2*p]     = (float)(ed * cos(yd * 2048.0));
        ws[WS_A64 + 2*p + 1] = (float)(ed * sin(yd * 2048.0));
    }
    // Apow[i] = Lb^{i+1}, i = 0..31
    for (int i = 0; i < 32; i++) {
        double m = (double)(i + 1);
        double ed = exp(zd * m);
        ws[WS_APOW + i*P2 + 2*p]     = (float)(ed * cos(yd * m));
        ws[WS_APOW + i*P2 + 2*p + 1] = (float)(ed * sin(yd * m));
    }
    // coef = (Lambda_bar - 1) / Lambda
    float lbr = ws[WS_LB + 2*p], lbi = ws[WS_LB + 2*p + 1];
    float a = lbr - 1.0f, b = lbi;
    float den = lr*lr + li*li;
    ws[WS_COEF + 2*p]     = (a*lr + b*li) / den;
    ws[WS_COEF + 2*p + 1] = (b*lr - a*li) / den;
}

// ---------------------------------------------------------------------------
// Setup 2: build split-bf16 packed weights, layout [n][k] (k contiguous).
__global__ void k_setup_mats(const float* __restrict__ B, const float* __restrict__ C,
                             const float* __restrict__ coef,
                             ushort* __restrict__ w1h, ushort* __restrict__ w1l,
                             ushort* __restrict__ w2h, ushort* __restrict__ w2l) {
    int t = blockIdx.x * blockDim.x + threadIdx.x;   // 0..16383
    for (int e = t; e < P_DIM * H_DIM; e += 64 * 256) {
        int p = e >> 8;          // 0..127
        int h = e & 255;         // 0..255
        float br = B[(size_t)(p*H_DIM + h)*2 + 0];
        float bi = B[(size_t)(p*H_DIM + h)*2 + 1];
        float cr = coef[2*p], ci = coef[2*p + 1];
        float v1r = cr*br - ci*bi;
        float v1i = cr*bi + ci*br;
        ushort hi, lo;
        split_bf16(v1r, hi, lo);
        w1h[(size_t)(2*p)*256 + h] = hi;  w1l[(size_t)(2*p)*256 + h] = lo;
        split_bf16(v1i, hi, lo);
        w1h[(size_t)(2*p+1)*256 + h] = hi; w1l[(size_t)(2*p+1)*256 + h] = lo;
        float Cr = C[(size_t)(h*P_DIM + p)*2 + 0];
        float Ci = C[(size_t)(h*P_DIM + p)*2 + 1];
        split_bf16(2.0f*Cr, hi, lo);
        w2h[(size_t)h*256 + 2*p] = hi;    w2l[(size_t)h*256 + 2*p] = lo;
        split_bf16(-2.0f*Ci, hi, lo);
        w2h[(size_t)h*256 + 2*p+1] = hi;  w2l[(size_t)h*256 + 2*p+1] = lo;
    }
}

// ---------------------------------------------------------------------------
// MFMA split-bf16 GEMM: C[l][n] = sum_k A[l][k] * W[k][n]
// M=32768, N=256 (full N per block -> in-place safe), K=256.
// APPLY: during A staging add Lb^{i+1} * carry[g] (fused scan_apply).
#define SAK 40   // LDS k-stride (ushorts): 32 + 8 pad, rows 16B aligned
#define SBK 40

template<bool EPI, bool APPLY>
__global__ __launch_bounds__(512, 2) void k_gemm_mfma(
        const float* A, const ushort* __restrict__ Wh, const ushort* __restrict__ Wl,
        float* Cmat, const float* __restrict__ Dv, const float* __restrict__ U,
        const float* __restrict__ ws) {
    __shared__ ushort Ah[128 * SAK];
    __shared__ ushort Al[128 * SAK];
    __shared__ ushort Bh[256 * SBK];
    __shared__ ushort Bl[256 * SBK];
    const int t      = threadIdx.x;
    const int lane   = t & 63;
    const int wave   = t >> 6;        // 0..7
    const int wm     = wave & 3;      // M quarter (32 rows each)
    const int wn     = wave >> 2;     // N half (128 cols each)
    const int lane16 = lane & 15;
    const int quad   = lane >> 4;
    const int l0     = blockIdx.x * 128;

    f32x4 acc[2][8];
    #pragma unroll
    for (int i = 0; i < 2; i++)
        #pragma unroll
        for (int j = 0; j < 8; j++) acc[i][j] = (f32x4){0.f, 0.f, 0.f, 0.f};

    for (int k0 = 0; k0 < 256; k0 += 32) {
        // stage A (fp32 -> split bf16): 128 rows x 32 k = 1024 float4s, 2/thread
        #pragma unroll
        for (int j = 0; j < 2; j++) {
            int idx = j * 512 + t;
            int m  = idx >> 3;
            int c4 = idx & 7;
            float4 f = *(const float4*)(A + (size_t)(l0 + m) * 256 + k0 + c4 * 4);
            if (APPLY) {
                int mg = l0 + m;
                int g  = mg >> 5, i = mg & 31;
                int j0 = k0 + c4 * 4;
                const float4 ap = *(const float4*)(ws + WS_APOW + (size_t)i * P2 + j0);
                const float4 cr = *(const float4*)(ws + WS_CARRY + (size_t)g * P2 + j0);
                f.x += ap.x * cr.x - ap.y * cr.y;
                f.y += ap.x * cr.y + ap.y * cr.x;
                f.z += ap.z * cr.z - ap.w * cr.w;
                f.w += ap.z * cr.w + ap.w * cr.z;
            }
            ushort4 h4, l4;
            split_bf16(f.x, h4.x, l4.x);
            split_bf16(f.y, h4.y, l4.y);
            split_bf16(f.z, h4.z, l4.z);
            split_bf16(f.w, h4.w, l4.w);
            *(ushort4*)(Ah + m * SAK + c4 * 4) = h4;
            *(ushort4*)(Al + m * SAK + c4 * 4) = l4;
        }
        // stage B (already split/packed [n][k]): 256 rows x 32 k
        #pragma unroll
        for (int j = 0; j < 2; j++) {
            int idx = j * 512 + t;
            int n = idx >> 2;
            int c = idx & 3;
            *(uint4*)(Bh + n * SBK + c * 8) = *(const uint4*)(Wh + (size_t)n * 256 + k0 + c * 8);
            *(uint4*)(Bl + n * SBK + c * 8) = *(const uint4*)(Wl + (size_t)n * 256 + k0 + c * 8);
        }
        __syncthreads();
        short8 ah[2], alo[2], bh[8], blo[8];
        #pragma unroll
        for (int mf = 0; mf < 2; mf++) {
            int m = wm * 32 + mf * 16 + lane16;
            ah[mf]  = *(const short8*)(Ah + m * SAK + quad * 8);
            alo[mf] = *(const short8*)(Al + m * SAK + quad * 8);
        }
        #pragma unroll
        for (int nf = 0; nf < 8; nf++) {
            int n = wn * 128 + nf * 16 + lane16;
            bh[nf]  = *(const short8*)(Bh + n * SBK + quad * 8);
            blo[nf] = *(const short8*)(Bl + n * SBK + quad * 8);
        }
        #pragma unroll
        for (int mf = 0; mf < 2; mf++)
            #pragma unroll
            for (int nf = 0; nf < 8; nf++) {
                acc[mf][nf] = __builtin_amdgcn_mfma_f32_16x16x32_bf16(ah[mf],  bh[nf],  acc[mf][nf], 0, 0, 0);
                acc[mf][nf] = __builtin_amdgcn_mfma_f32_16x16x32_bf16(ah[mf],  blo[nf], acc[mf][nf], 0, 0, 0);
                acc[mf][nf] = __builtin_amdgcn_mfma_f32_16x16x32_bf16(alo[mf], bh[nf],  acc[mf][nf], 0, 0, 0);
            }
        __syncthreads();
    }
    // epilogue: C/D layout col=lane&15, row=quad*4+reg
    #pragma unroll
    for (int mf = 0; mf < 2; mf++) {
        #pragma unroll
        for (int nf = 0; nf < 8; nf++) {
            int row0 = l0 + wm * 32 + mf * 16 + quad * 4;
            int col  = wn * 128 + nf * 16 + lane16;
            #pragma unroll
            for (int r = 0; r < 4; r++) {
                float v = acc[mf][nf][r];
                if (EPI) {
                    v += Dv[col] * U[(size_t)(row0 + r) * 256 + col];
                }
                Cmat[(size_t)(row0 + r) * 256 + col] = v;
            }
        }
    }
}

// ---------------------------------------------------------------------------
// Scan pass 1: local (zero-carry) scan in place; store chunk-end state.
__global__ void k_scan_local(float* __restrict__ bu, float* __restrict__ ws) {
    const int t = threadIdx.x;
    const int g = blockIdx.x * 4 + (t >> 6);
    const int q = t & 63;
    const float4 A = *(const float4*)(ws + WS_LB + 4 * q);
    float x0r = 0.f, x0i = 0.f, x1r = 0.f, x1i = 0.f;
    float* base = bu + (size_t)g * T_CHUNK * 256 + 4 * q;
    #pragma unroll 8
    for (int i = 0; i < T_CHUNK; i++) {
        float4 f = *(float4*)(base + (size_t)i * 256);
        float n0r = A.x * x0r - A.y * x0i + f.x;
        float n0i = A.x * x0i + A.y * x0r + f.y;
        float n1r = A.z * x1r - A.w * x1i + f.z;
        float n1i = A.z * x1i + A.w * x1r + f.w;
        x0r = n0r; x0i = n0i; x1r = n1r; x1i = n1i;
        *(float4*)(base + (size_t)i * 256) = make_float4(x0r, x0i, x1r, x1i);
    }
    *(float4*)(ws + WS_XEND + (size_t)g * 256 + 4 * q) = make_float4(x0r, x0i, x1r, x1i);
}

// Scan pass 2 (parallel): 1 block x 1024 threads = 16 segments x 64 lanes.
// Segment s covers chunks [64s, 64s+64). Lane q owns channels 2q, 2q+1.
__global__ __launch_bounds__(1024) void k_scan_carry(float* __restrict__ ws) {
    __shared__ float Esh[16 * P2];
    const int t = threadIdx.x;
    const int s = t >> 6;      // segment 0..15 (wave-uniform)
    const int q = t & 63;
    const float4 A   = *(const float4*)(ws + WS_AT  + 4 * q);   // Lb^32
    const float4 A64 = *(const float4*)(ws + WS_A64 + 4 * q);   // Lb^2048
    const float* xe = ws + WS_XEND + (size_t)s * 64 * P2 + 4 * q;
    // phase A: segment-local reduction E_s = sum_j A^{63-j} xend[64s+j]
    float e0r = 0.f, e0i = 0.f, e1r = 0.f, e1i = 0.f;
    #pragma unroll 4
    for (int j = 0; j < 64; j++) {
        float4 x = *(const float4*)(xe + (size_t)j * P2);
        float n0r = A.x * e0r - A.y * e0i + x.x;
        float n0i = A.x * e0i + A.y * e0r + x.y;
        float n1r = A.z * e1r - A.w * e1i + x.z;
        float n1i = A.z * e1i + A.w * e1r + x.w;
        e0r = n0r; e0i = n0i; e1r = n1r; e1i = n1i;
    }
    *(float4*)(Esh + s * P2 + 4 * q) = make_float4(e0r, e0i, e1r, e1i);
    __syncthreads();
    // phase B: c_s = recurrence over segments j < s with A64
    float c0r = 0.f, c0i = 0.f, c1r = 0.f, c1i = 0.f;
    for (int j = 0; j < s; j++) {
        float4 E = *(const float4*)(Esh + j * P2 + 4 * q);
        float n0r = A64.x * c0r - A64.y * c0i + E.x;
        float n0i = A64.x * c0i + A64.y * c0r + E.y;
        float n1r = A64.z * c1r - A64.w * c1i + E.z;
        float n1i = A64.z * c1i + A64.w * c1r + E.w;
        c0r = n0r; c0i = n0i; c1r = n1r; c1i = n1i;
    }
    // phase C: walk segment writing carry[g], then advancing with xend[g]
    float* cw = ws + WS_CARRY + (size_t)s * 64 * P2 + 4 * q;
    #pragma unroll 4
    for (int j = 0; j < 64; j++) {
        *(float4*)(cw + (size_t)j * P2) = make_float4(c0r, c0i, c1r, c1i);
        float4 x = *(const float4*)(xe + (size_t)j * P2);
        float n0r = A.x * c0r - A.y * c0i + x.x;
        float n0i = A.x * c0i + A.y * c0r + x.y;
        float n1r = A.z * c1r - A.w * c1i + x.z;
        float n1i = A.z * c1i + A.w * c1r + x.w;
        c0r = n0r; c0i = n0i; c1r = n1r; c1i = n1i;
    }
}

// ---------------------------------------------------------------------------
extern "C" void kernel_launch(void* const* d_in, const int* in_sizes, int n_in,
                              void* d_out, int out_size, void* d_ws, size_t ws_size,
                              hipStream_t stream) {
    const float* lre   = (const float*)d_in[0];  // Lambda_re (P)
    const float* lim   = (const float*)d_in[1];  // Lambda_im (P)
    const float* B     = (const float*)d_in[2];  // (P,H,2)
    const float* C     = (const float*)d_in[3];  // (H,P,2)
    const float* D     = (const float*)d_in[4];  // (H)
    const float* lstep = (const float*)d_in[5];  // (P)
    const float* u     = (const float*)d_in[6];  // (L,H)
    float* out = (float*)d_out;                  // (L,H) -- also Bu/xs scratch
    float* ws  = (float*)d_ws;
    ushort* wpk = (ushort*)(ws + WS_PACKS);
    ushort* w1h = wpk;
    ushort* w1l = wpk + 65536;
    ushort* w2h = wpk + 131072;
    ushort* w2l = wpk + 196608;

    k_setup_p<<<1, 128, 0, stream>>>(lre, lim, lstep, ws);
    k_setup_mats<<<64, 256, 0, stream>>>(B, C, ws + WS_COEF, w1h, w1l, w2h, w2l);
    // Bu = u @ W1  -> into d_out
    k_gemm_mfma<false, false><<<256, 512, 0, stream>>>(u, w1h, w1l, out, nullptr, nullptr, ws);
    // chunked linear scan: local pass in place, parallel carry pass
    k_scan_local<<<256, 256, 0, stream>>>(out, ws);
    k_scan_carry<<<1, 1024, 0, stream>>>(ws);
    // out = (xs_local + Lb^{i+1} carry) @ W2 + D*u  (apply fused into staging)
    k_gemm_mfma<true, true><<<256, 512, 0, stream>>>(out, w2h, w2l, out, D, u, ws);
}